// Round 6
// baseline (276.637 us; speedup 1.0000x reference)
//
#include <hip/hip_runtime.h>
#include <math.h>

#define GSZ 52
#define NA 3
#define NCLS 80
#define CH 85                     // 5 + NCLS
#define NCA (GSZ*GSZ*NA)          // 8112 cell-anchors per batch
#define MAXGT 64
#define RPC 16                    // records per chunk
#define CHF (RPC*CH)              // 1360 floats per tensor-chunk
#define CHF4 (CHF/4)              // 340 float4 per tensor-chunk
#define CPB 8                     // chunks per block (software-pipelined)
#define RPB (RPC*CPB)             // 128 records per kA block

__device__ __forceinline__ float softplus_fast(float x) {
    return fmaxf(x, 0.0f) + __logf(1.0f + __expf(-fabsf(x)));
}

// ws layout: cnt[32] ints @0 | accum[8] floats @128 | done int @160 | gtbox @256
__global__ void k_init(int* ws32) {
    if (threadIdx.x < 48) ws32[threadIdx.x] = 0;
}

// Persistent software-pipelined staging: double-buffered LDS chunks with
// register prefetch. Per chunk: write LDS buf p, issue next chunk's global
// loads, ONE barrier, process buf p (next loads stay in flight).
// Buf p is rewritten two iterations after its last read -> the single
// barrier per iteration covers the WAR hazard.
__global__ __launch_bounds__(256, 7)
void kA(const float* __restrict__ tg, const float* __restrict__ pr,
        const float* __restrict__ anchors,
        int* __restrict__ cnt, float* __restrict__ accum,
        float4* __restrict__ gtbox,
        float4* __restrict__ boxout, float* __restrict__ confout) {
    __shared__ float sT[2][CHF];
    __shared__ float sP[2][CHF];
    const int tid = threadIdx.x;
    const size_t rec_blk = (size_t)blockIdx.x * RPB;
    const bool g2 = tid < (CHF4 - 256);      // tid < 84

    float a_txty = 0.f, a_twth = 0.f, a_obj = 0.f, a_cls = 0.f;

    // prologue: chunk 0 loads
    float4 t0, t1, p0, p1;
    {
        const float4* gT = (const float4*)(tg + rec_blk * CH);
        const float4* gP = (const float4*)(pr + rec_blk * CH);
        t0 = gT[tid]; p0 = gP[tid];
        if (g2) { t1 = gT[256 + tid]; p1 = gP[256 + tid]; }
    }

#pragma unroll
    for (int j = 0; j < CPB; j++) {
        const int p = j & 1;
        float4* dT = (float4*)sT[p];
        float4* dP = (float4*)sP[p];
        dT[tid] = t0; dP[tid] = p0;
        if (g2) { dT[256 + tid] = t1; dP[256 + tid] = p1; }

        if (j + 1 < CPB) {       // prefetch chunk j+1 (in flight across barrier)
            size_t rec0n = rec_blk + (size_t)(j + 1) * RPC;
            const float4* gT = (const float4*)(tg + rec0n * CH);
            const float4* gP = (const float4*)(pr + rec0n * CH);
            t0 = gT[tid]; p0 = gP[tid];
            if (g2) { t1 = gT[256 + tid]; p1 = gP[256 + tid]; }
        }
        __syncthreads();

        if (tid < RPC) {
            const float* rT = &sT[p][tid * CH];   // stride 85: conflict-free
            const float* rP = &sP[p][tid * CH];
            size_t rec = rec_blk + (size_t)j * RPC + tid;
            int b    = (int)(rec / NCA);
            int nloc = (int)(rec - (size_t)b * NCA);
            int a    = nloc % NA;
            int cell = nloc / NA;
            int gi = cell / GSZ, gj = cell % GSZ;
            float aw = anchors[2 * a], ah = anchors[2 * a + 1];

            float sx = __builtin_amdgcn_rcpf(1.f + __expf(-rP[0]));
            float sy = __builtin_amdgcn_rcpf(1.f + __expf(-rP[1]));
            float bw = __expf(rP[2]) * aw;
            float bh = __expf(rP[3]) * ah;
            float pconf = rP[4];
            bool isobj = rT[4] > 0.f;

            if (isobj) {
                float4 g = make_float4(rT[0], rT[1], rT[2], rT[3]);
                int pos = atomicAdd(&cnt[b], 1);
                if (pos < MAXGT) gtbox[b * MAXGT + pos] = g;

                float scale = 2.f - (g.z * (1.f / 416.f)) * (g.w * (1.f / 416.f));
                float dx = sx - (g.x * 0.125f - (float)gj);
                float dy = sy - (g.y * 0.125f - (float)gi);
                a_txty += (dx * dx + dy * dy) * scale;

                float rw = __builtin_amdgcn_rcpf(aw), rh = __builtin_amdgcn_rcpf(ah);
                float pwr = fminf(fmaxf(bw * rw, 1e-9f), 1e9f);
                float phr = fminf(fmaxf(bh * rh, 1e-9f), 1e9f);
                float twr = fminf(fmaxf(g.z * rw, 1e-9f), 1e9f);
                float thr = fminf(fmaxf(g.w * rh, 1e-9f), 1e9f);
                float dw = __logf(pwr) - __logf(twr);
                float dh = __logf(phr) - __logf(thr);
                a_twth += (dw * dw + dh * dh) * scale;

                a_obj += softplus_fast(pconf) - pconf;    // conf target == 1

                int cid = 0;
                float cls = 0.f;
                for (int c = 0; c < NCLS; c++) {
                    if (rT[5 + c] > 0.5f) cid = c;        // one-hot target
                    cls += softplus_fast(rP[5 + c]);
                }
                cls -= rP[5 + cid];
                a_cls += cls;
            }
            // compact SoA; isobj packed as sign of box.z (bw > 0 always)
            boxout[rec]  = make_float4((sx + (float)gj) * 8.f,
                                       (sy + (float)gi) * 8.f,
                                       isobj ? -bw : bw, bh);
            confout[rec] = pconf;
        }
    }

    // owners live in wave 0 -> single-wave reduce, atomics by lane 0
    if (tid < 64) {
        for (int off = 32; off > 0; off >>= 1) {
            a_txty += __shfl_down(a_txty, off);
            a_twth += __shfl_down(a_twth, off);
            a_obj  += __shfl_down(a_obj,  off);
            a_cls  += __shfl_down(a_cls,  off);
        }
        if (tid == 0 && (a_txty != 0.f || a_twth != 0.f || a_obj != 0.f || a_cls != 0.f)) {
            atomicAdd(&accum[0], a_txty);
            atomicAdd(&accum[1], a_twth);
            atomicAdd(&accum[3], a_obj);
            atomicAdd(&accum[4], a_cls);
        }
    }
}

// noobj loss over compact SoA + final output write via last-block ticket.
__global__ __launch_bounds__(256)
void kB(const int* __restrict__ cnt, const float4* __restrict__ gtbox,
        const float4* __restrict__ boxin, const float* __restrict__ confin,
        float* __restrict__ accum, int* __restrict__ done, int B,
        float* __restrict__ out) {
    __shared__ float4 sbox[2 * MAXGT];
    __shared__ float  sw[4];
    __shared__ int    sm[2];

    int tid = threadIdx.x;
    size_t rec = (size_t)blockIdx.x * 256 + tid;       // grid*256 == B*NCA
    int b0 = (int)(((size_t)blockIdx.x * 256) / NCA);
    int b1 = (int)(((size_t)blockIdx.x * 256 + 255) / NCA);

    if (tid < MAXGT)          sbox[tid] = gtbox[b0 * MAXGT + tid];
    else if (tid < 2 * MAXGT) sbox[tid] = gtbox[b1 * MAXGT + (tid - MAXGT)];
    if (tid == 0) { sm[0] = min(cnt[b0], MAXGT); sm[1] = min(cnt[b1], MAXGT); }
    __syncthreads();

    int b = (int)(rec / NCA);
    int base = (b == b0) ? 0 : MAXGT;
    int m    = (b == b0) ? sm[0] : sm[1];

    float4 pb = boxin[rec];
    float pconf = confin[rec];
    float v = 0.f;
    if (pb.z > 0.f) {                                  // non-obj cell
        float bw = pb.z, bh = pb.w;
        float px0 = pb.x - bw * 0.5f, px1 = pb.x + bw * 0.5f;
        float py0 = pb.y - bh * 0.5f, py1 = pb.y + bh * 0.5f;
        float areap = bw * bh;
        float best = 0.f;
        for (int k = 0; k < m; k++) {
            float4 q = sbox[base + k];
            float ix = fminf(px1, q.x + q.z * 0.5f) - fmaxf(px0, q.x - q.z * 0.5f);
            float iy = fminf(py1, q.y + q.w * 0.5f) - fmaxf(py0, q.y - q.w * 0.5f);
            float inter = fmaxf(ix, 0.f) * fmaxf(iy, 0.f);
            float u = areap + q.z * q.w - inter + 1e-9f;
            best = fmaxf(best, inter * __builtin_amdgcn_rcpf(u));
        }
        if (best < 0.6f) v = softplus_fast(pconf);
    }

    int lane = tid & 63, wv = tid >> 6;
    for (int off = 32; off > 0; off >>= 1) v += __shfl_down(v, off);
    if (lane == 0) sw[wv] = v;
    __syncthreads();
    if (tid == 0) {
        atomicAdd(&accum[2], sw[0] + sw[1] + sw[2] + sw[3]);
        __threadfence();
        int t = atomicAdd(done, 1);
        if (t == (int)gridDim.x - 1) {                 // last block finalizes
            float invB = 1.f / (float)B;
            float tot = 0.f;
#pragma unroll
            for (int i = 0; i < 5; i++) {
                float r = atomicAdd(&accum[i], 0.f) * invB;
                out[i] = r;
                tot += r;
            }
            out[5] = tot;
        }
    }
}

extern "C" void kernel_launch(void* const* d_in, const int* in_sizes, int n_in,
                              void* d_out, int out_size, void* d_ws, size_t ws_size,
                              hipStream_t stream) {
    const float* preds   = (const float*)d_in[0];
    const float* targets = (const float*)d_in[1];
    const float* anchors = (const float*)d_in[2];
    float* out = (float*)d_out;

    int B = in_sizes[0] / (NCA * CH);                 // 32
    size_t total_rec = (size_t)B * NCA;               // 259584

    char* ws = (char*)d_ws;
    int*    cnt   = (int*)ws;                         // 32 ints  @0
    float*  accum = (float*)(ws + 128);               // 8 floats @128
    int*    done  = (int*)(ws + 160);                 // 1 int    @160
    float4* gtbox = (float4*)(ws + 256);              // B*64 float4
    size_t off = 256 + (size_t)B * MAXGT * sizeof(float4);
    off = (off + 15) & ~(size_t)15;
    float4* boxout  = (float4*)(ws + off);  off += total_rec * sizeof(float4);
    float*  confout = (float*)(ws + off);

    int gA = (int)(total_rec / RPB);                  // 2028
    int gB = (int)(total_rec / 256);                  // 1014

    k_init<<<1, 64, 0, stream>>>((int*)ws);
    kA<<<gA, 256, 0, stream>>>(targets, preds, anchors, cnt, accum,
                               gtbox, boxout, confout);
    kB<<<gB, 256, 0, stream>>>(cnt, gtbox, boxout, confout, accum, done, B, out);
}

// Round 7
// 251.731 us; speedup vs baseline: 1.0989x; 1.0989x over previous
//
#include <hip/hip_runtime.h>
#include <math.h>

#define GSZ 52
#define NA 3
#define NCLS 80
#define CH 85                     // 5 + NCLS
#define NCA (GSZ*GSZ*NA)          // 8112 cell-anchors per batch
#define MAXGT 64
#define RPB 32                    // records per kA block (one-shot)
#define FPC (RPB*CH)              // 2720 floats per staged tensor chunk
#define F4PC (FPC/4)              // 680 float4 per tensor chunk

__device__ __forceinline__ float softplus_fast(float x) {
    return fmaxf(x, 0.0f) + __logf(1.0f + __expf(-fabsf(x)));
}

// ws layout: cnt[32] ints @0 | accum[8] floats @128 | done int @160 | gtbox @256
__global__ void k_init(int* ws32) {
    if (threadIdx.x < 48) ws32[threadIdx.x] = 0;
}

// One-shot coalesced staging (R3 shape: 8112 independent blocks, max TLP),
// fused with box decode + ALL obj-cell losses + compact SoA emit.
__global__ void kA(const float* __restrict__ tg, const float* __restrict__ pr,
                   const float* __restrict__ anchors,
                   int* __restrict__ cnt, float* __restrict__ accum,
                   float4* __restrict__ gtbox,
                   float4* __restrict__ boxout, float* __restrict__ confout) {
    __shared__ float sT[FPC];
    __shared__ float sP[FPC];
    const int tid = threadIdx.x;
    const size_t rec0 = (size_t)blockIdx.x * RPB;

    // stage both tensors, 6 independent float4 loads in flight per thread
    {
        const float4* gT = (const float4*)(tg + rec0 * CH);  // 10880B/block: 64B-aligned
        const float4* gP = (const float4*)(pr + rec0 * CH);
        float4* dT = (float4*)sT;
        float4* dP = (float4*)sP;
        bool g2 = (tid + 512) < F4PC;                        // tid < 168
        float4 t0 = gT[tid],       p0 = gP[tid];
        float4 t1 = gT[tid + 256], p1 = gP[tid + 256];
        float4 t2, p2;
        if (g2) { t2 = gT[tid + 512]; p2 = gP[tid + 512]; }
        dT[tid] = t0;       dP[tid] = p0;
        dT[tid + 256] = t1; dP[tid + 256] = p1;
        if (g2) { dT[tid + 512] = t2; dP[tid + 512] = p2; }
    }
    __syncthreads();

    float a_txty = 0.f, a_twth = 0.f, a_obj = 0.f, a_cls = 0.f;

    if (tid < RPB) {
        const float* rT = sT + tid * CH;    // stride 85: gcd(85,32)=1, conflict-free
        const float* rP = sP + tid * CH;
        size_t rec = rec0 + tid;
        int b    = (int)(rec / NCA);
        int nloc = (int)(rec - (size_t)b * NCA);
        int a    = nloc % NA;
        int cell = nloc / NA;
        int gi = cell / GSZ, gj = cell % GSZ;
        float aw = anchors[2 * a], ah = anchors[2 * a + 1];

        float sx = __builtin_amdgcn_rcpf(1.f + __expf(-rP[0]));
        float sy = __builtin_amdgcn_rcpf(1.f + __expf(-rP[1]));
        float bw = __expf(rP[2]) * aw;
        float bh = __expf(rP[3]) * ah;
        float pconf = rP[4];
        bool isobj = rT[4] > 0.f;

        if (isobj) {
            float4 g = make_float4(rT[0], rT[1], rT[2], rT[3]);
            int pos = atomicAdd(&cnt[b], 1);
            if (pos < MAXGT) gtbox[b * MAXGT + pos] = g;

            float scale = 2.f - (g.z * (1.f / 416.f)) * (g.w * (1.f / 416.f));
            float dx = sx - (g.x * 0.125f - (float)gj);
            float dy = sy - (g.y * 0.125f - (float)gi);
            a_txty = (dx * dx + dy * dy) * scale;

            float rw = __builtin_amdgcn_rcpf(aw), rh = __builtin_amdgcn_rcpf(ah);
            float pwr = fminf(fmaxf(bw * rw, 1e-9f), 1e9f);
            float phr = fminf(fmaxf(bh * rh, 1e-9f), 1e9f);
            float twr = fminf(fmaxf(g.z * rw, 1e-9f), 1e9f);
            float thr = fminf(fmaxf(g.w * rh, 1e-9f), 1e9f);
            float dw = __logf(pwr) - __logf(twr);
            float dh = __logf(phr) - __logf(thr);
            a_twth = (dw * dw + dh * dh) * scale;

            a_obj = softplus_fast(pconf) - pconf;     // conf target == 1 exactly

            int cid = 0;
            float cls = 0.f;
            for (int c = 0; c < NCLS; c++) {
                if (rT[5 + c] > 0.5f) cid = c;        // one-hot target
                cls += softplus_fast(rP[5 + c]);
            }
            cls -= rP[5 + cid];
            a_cls = cls;
        }
        // compact SoA; isobj packed as sign of box.z (bw > 0 always)
        boxout[rec]  = make_float4((sx + (float)gj) * 8.f,
                                   (sy + (float)gi) * 8.f,
                                   isobj ? -bw : bw, bh);
        confout[rec] = pconf;
    }

    // owners all live in wave 0: intra-wave reduce, 4 atomics by lane 0
    if (tid < 64) {
        for (int off = 32; off > 0; off >>= 1) {
            a_txty += __shfl_down(a_txty, off);
            a_twth += __shfl_down(a_twth, off);
            a_obj  += __shfl_down(a_obj,  off);
            a_cls  += __shfl_down(a_cls,  off);
        }
        if (tid == 0 && (a_txty != 0.f || a_twth != 0.f || a_obj != 0.f || a_cls != 0.f)) {
            atomicAdd(&accum[0], a_txty);
            atomicAdd(&accum[1], a_twth);
            atomicAdd(&accum[3], a_obj);
            atomicAdd(&accum[4], a_cls);
        }
    }
}

// noobj loss over compact SoA + final output write via last-block ticket.
__global__ __launch_bounds__(256)
void kB(const int* __restrict__ cnt, const float4* __restrict__ gtbox,
        const float4* __restrict__ boxin, const float* __restrict__ confin,
        float* __restrict__ accum, int* __restrict__ done, int B,
        float* __restrict__ out) {
    __shared__ float4 sbox[2 * MAXGT];
    __shared__ float  sw[4];
    __shared__ int    sm[2];

    int tid = threadIdx.x;
    size_t rec = (size_t)blockIdx.x * 256 + tid;       // grid*256 == B*NCA
    int b0 = (int)(((size_t)blockIdx.x * 256) / NCA);
    int b1 = (int)(((size_t)blockIdx.x * 256 + 255) / NCA);

    if (tid < MAXGT)          sbox[tid] = gtbox[b0 * MAXGT + tid];
    else if (tid < 2 * MAXGT) sbox[tid] = gtbox[b1 * MAXGT + (tid - MAXGT)];
    if (tid == 0) { sm[0] = min(cnt[b0], MAXGT); sm[1] = min(cnt[b1], MAXGT); }
    __syncthreads();

    int b = (int)(rec / NCA);
    int base = (b == b0) ? 0 : MAXGT;
    int m    = (b == b0) ? sm[0] : sm[1];

    float4 pb = boxin[rec];
    float pconf = confin[rec];
    float v = 0.f;
    if (pb.z > 0.f) {                                  // non-obj cell
        float bw = pb.z, bh = pb.w;
        float px0 = pb.x - bw * 0.5f, px1 = pb.x + bw * 0.5f;
        float py0 = pb.y - bh * 0.5f, py1 = pb.y + bh * 0.5f;
        float areap = bw * bh;
        float best = 0.f;
        for (int k = 0; k < m; k++) {
            float4 q = sbox[base + k];
            float ix = fminf(px1, q.x + q.z * 0.5f) - fmaxf(px0, q.x - q.z * 0.5f);
            float iy = fminf(py1, q.y + q.w * 0.5f) - fmaxf(py0, q.y - q.w * 0.5f);
            float inter = fmaxf(ix, 0.f) * fmaxf(iy, 0.f);
            float u = areap + q.z * q.w - inter + 1e-9f;
            best = fmaxf(best, inter * __builtin_amdgcn_rcpf(u));
        }
        if (best < 0.6f) v = softplus_fast(pconf);
    }

    int lane = tid & 63, wv = tid >> 6;
    for (int off = 32; off > 0; off >>= 1) v += __shfl_down(v, off);
    if (lane == 0) sw[wv] = v;
    __syncthreads();
    if (tid == 0) {
        atomicAdd(&accum[2], sw[0] + sw[1] + sw[2] + sw[3]);
        __threadfence();
        int t = atomicAdd(done, 1);
        if (t == (int)gridDim.x - 1) {                 // last block finalizes
            float invB = 1.f / (float)B;
            float tot = 0.f;
#pragma unroll
            for (int i = 0; i < 5; i++) {
                float r = atomicAdd(&accum[i], 0.f) * invB;
                out[i] = r;
                tot += r;
            }
            out[5] = tot;
        }
    }
}

extern "C" void kernel_launch(void* const* d_in, const int* in_sizes, int n_in,
                              void* d_out, int out_size, void* d_ws, size_t ws_size,
                              hipStream_t stream) {
    const float* preds   = (const float*)d_in[0];
    const float* targets = (const float*)d_in[1];
    const float* anchors = (const float*)d_in[2];
    float* out = (float*)d_out;

    int B = in_sizes[0] / (NCA * CH);                 // 32
    size_t total_rec = (size_t)B * NCA;               // 259584

    char* ws = (char*)d_ws;
    int*    cnt   = (int*)ws;                         // 32 ints  @0
    float*  accum = (float*)(ws + 128);               // 8 floats @128
    int*    done  = (int*)(ws + 160);                 // 1 int    @160
    float4* gtbox = (float4*)(ws + 256);              // B*64 float4
    size_t off = 256 + (size_t)B * MAXGT * sizeof(float4);
    off = (off + 15) & ~(size_t)15;
    float4* boxout  = (float4*)(ws + off);  off += total_rec * sizeof(float4);
    float*  confout = (float*)(ws + off);

    int gA = (int)(total_rec / RPB);                  // 8112
    int gB = (int)(total_rec / 256);                  // 1014

    k_init<<<1, 64, 0, stream>>>((int*)ws);
    kA<<<gA, 256, 0, stream>>>(targets, preds, anchors, cnt, accum,
                               gtbox, boxout, confout);
    kB<<<gB, 256, 0, stream>>>(cnt, gtbox, boxout, confout, accum, done, B, out);
}